// Round 1
// baseline (77.520 us; speedup 1.0000x reference)
//
#include <hip/hip_runtime.h>

#define NCODES 512
#define DIM 128
#define NROWS (64*2048)          // 131072
#define QN (NROWS*DIM)           // 16777216
#define BLK_ROWS 512
#define NBLOCKS (NROWS/BLK_ROWS) // 256
#define NWAVES 16

typedef __attribute__((ext_vector_type(8))) short short8;
typedef __attribute__((ext_vector_type(4))) float f32x4;

__device__ __forceinline__ unsigned short f2bf(float f) {
  unsigned u = __builtin_bit_cast(unsigned, f);
  u += 0x7FFFu + ((u >> 16) & 1u);   // RNE
  return (unsigned short)(u >> 16);
}
__device__ __forceinline__ float bf2f(unsigned short h) {
  unsigned u = ((unsigned)h) << 16;
  return __builtin_bit_cast(float, u);
}

// ---------------- prep: bf16 codebook + per-code weights ----------------
__global__ void vq_prep(const float* __restrict__ emb, const float* __restrict__ scaling,
                        unsigned short* __restrict__ emb_bf,
                        float* __restrict__ wv, float* __restrict__ wse) {
  int k = blockIdx.x;
  int l = threadIdx.x; // 64 lanes
  float2 v = ((const float2*)(emb + k * DIM))[l];
  float ss = v.x * v.x + v.y * v.y;
#pragma unroll
  for (int m = 1; m < 64; m <<= 1) ss += __shfl_xor(ss, m);
  unsigned pack = (unsigned)f2bf(v.x) | ((unsigned)f2bf(v.y) << 16);
  ((unsigned*)emb_bf)[k * 64 + l] = pack;
  if (l == 0) {
    float hr = 40.0f + (float)k * (140.0f / 511.0f);
    float wt = 1.0f + scaling[k] * ((hr - 100.0f) * (1.0f / 70.0f));
    wv[k] = wt;
    wse[k] = wt * ss;  // w_k * ||e_k||^2
  }
}

// ---------------- main ----------------
struct SmemT {
  unsigned short emb[NCODES * DIM]; // 131072 B, XOR-swizzled 16B slots
  float w[NCODES];
  float wse[NCODES];
};

__global__ __launch_bounds__(1024, 4) void vq_main(
    const float* __restrict__ x,
    const unsigned short* __restrict__ emb_bf,
    const float* __restrict__ wv,
    const float* __restrict__ wse,
    float* __restrict__ out_q,
    float* __restrict__ out_idx,
    float* __restrict__ partials) {
  __shared__ SmemT sm;
  const int tid = threadIdx.x;

  // Stage codebook into LDS with XOR swizzle: row = code (256 B = 16 slots of
  // 16 B); phys_slot = slot ^ (code&7) so a 16-lane column read spans 8 bank
  // groups (2-way = free, per G4/m136).
  {
    const uint4* src = (const uint4*)emb_bf;
#pragma unroll
    for (int i = 0; i < 8; i++) {
      int chunk = tid + i * 1024;        // 0..8191
      int code = chunk >> 4, slot = chunk & 15;
      uint4 d = src[chunk];
      int ps = slot ^ (code & 7);
      *(uint4*)((char*)sm.emb + code * 256 + ps * 16) = d;
    }
    if (tid < NCODES) { sm.w[tid] = wv[tid]; sm.wse[tid] = wse[tid]; }
  }
  __syncthreads();

  const int wave = tid >> 6, lane = tid & 63;
  const int g = lane >> 4, lr = lane & 15;
  const long rowbase = (long)blockIdx.x * BLK_ROWS + wave * 32;

  // A fragments (16x16x32 bf16): row = lane&15, k = (lane>>4)*8 + j, 4 chunks
  // of K=32 cover K=128. Two row-groups per wave (B-frag reuse).
  short8 a[2][4];
  float sr[2][4];  // ||x||^2 for C-layout rows 4*(lane>>4)+r
  {
    float srow[2];
#pragma unroll
    for (int rg = 0; rg < 2; rg++) {
      const float* xr = x + (rowbase + rg * 16 + lr) * DIM + g * 8;
      float ss = 0.f;
#pragma unroll
      for (int c = 0; c < 4; c++) {
        float4 v0 = *(const float4*)(xr + c * 32);
        float4 v1 = *(const float4*)(xr + c * 32 + 4);
        ss += v0.x * v0.x + v0.y * v0.y + v0.z * v0.z + v0.w * v0.w;
        ss += v1.x * v1.x + v1.y * v1.y + v1.z * v1.z + v1.w * v1.w;
        short8 av;
        av[0] = (short)f2bf(v0.x); av[1] = (short)f2bf(v0.y);
        av[2] = (short)f2bf(v0.z); av[3] = (short)f2bf(v0.w);
        av[4] = (short)f2bf(v1.x); av[5] = (short)f2bf(v1.y);
        av[6] = (short)f2bf(v1.z); av[7] = (short)f2bf(v1.w);
        a[rg][c] = av;
      }
      ss += __shfl_xor(ss, 16);
      ss += __shfl_xor(ss, 32);
      srow[rg] = ss;  // all 4 lanes with this lane&15 now hold s[row=lr]
    }
#pragma unroll
    for (int rg = 0; rg < 2; rg++)
#pragma unroll
      for (int r = 0; r < 4; r++)
        sr[rg][r] = __shfl(srow[rg], g * 4 + r);  // s of C-row 4g+r
  }

  // Sweep 32 column tiles of 16 codes; running weighted-argmin per lane.
  float vmin[2][4];
  int imin[2][4];
#pragma unroll
  for (int rg = 0; rg < 2; rg++)
#pragma unroll
    for (int r = 0; r < 4; r++) { vmin[rg][r] = 3.0e38f; imin[rg][r] = 0; }

  for (int t = 0; t < 32; t++) {
    const int code = t * 16 + lr;         // B col = lane&15
    const float wt = sm.w[code];
    const float bb = sm.wse[code];
    const float m2w = -2.0f * wt;
    f32x4 acc0 = {0.f, 0.f, 0.f, 0.f};
    f32x4 acc1 = {0.f, 0.f, 0.f, 0.f};
#pragma unroll
    for (int c = 0; c < 4; c++) {
      int ps = (4 * c + g) ^ (code & 7);
      short8 bf = *(const short8*)((char*)sm.emb + code * 256 + ps * 16);
      acc0 = __builtin_amdgcn_mfma_f32_16x16x32_bf16(a[0][c], bf, acc0, 0, 0, 0);
      acc1 = __builtin_amdgcn_mfma_f32_16x16x32_bf16(a[1][c], bf, acc1, 0, 0, 0);
    }
#pragma unroll
    for (int r = 0; r < 4; r++) {
      float v0 = fmaf(m2w, acc0[r], fmaf(wt, sr[0][r], bb));
      float v1 = fmaf(m2w, acc1[r], fmaf(wt, sr[1][r], bb));
      if (v0 < vmin[0][r]) { vmin[0][r] = v0; imin[0][r] = code; }
      if (v1 < vmin[1][r]) { vmin[1][r] = v1; imin[1][r] = code; }
    }
  }

  // Butterfly min-reduce across the 16 lanes of each C-row group
  // (tie -> smaller index, matching argmin-first semantics).
#pragma unroll
  for (int m = 1; m <= 8; m <<= 1) {
#pragma unroll
    for (int rg = 0; rg < 2; rg++)
#pragma unroll
      for (int r = 0; r < 4; r++) {
        float ov = __shfl_xor(vmin[rg][r], m);
        int oi = __shfl_xor(imin[rg][r], m);
        if (ov < vmin[rg][r] || (ov == vmin[rg][r] && oi < imin[rg][r])) {
          vmin[rg][r] = ov; imin[rg][r] = oi;
        }
      }
  }

  // Write indices (as float; output buffer is read back as f32).
  if (lr == 0) {
#pragma unroll
    for (int rg = 0; rg < 2; rg++)
#pragma unroll
      for (int r = 0; r < 4; r++)
        out_idx[rowbase + rg * 16 + g * 4 + r] = (float)imin[rg][r];
  }

  // Get the winning index for THIS lane's A-rows (row = lane&15).
  int myidx[2];
  {
    const int srcl = (lr >> 2) << 4;  // a lane in group lr>>2 (holds rows 4*(lr>>2)+r)
    const int sel = lr & 3;
#pragma unroll
    for (int rg = 0; rg < 2; rg++) {
      int c0 = __shfl(imin[rg][0], srcl);
      int c1 = __shfl(imin[rg][1], srcl);
      int c2 = __shfl(imin[rg][2], srcl);
      int c3 = __shfl(imin[rg][3], srcl);
      int lo = (sel & 1) ? c1 : c0;
      int hi = (sel & 1) ? c3 : c2;
      myidx[rg] = (sel & 2) ? hi : lo;
    }
  }

  // Quantized output (gather from LDS bf16 codebook, store as f32) + loss.
  float lacc = 0.f;
#pragma unroll
  for (int rg = 0; rg < 2; rg++) {
    const int code = myidx[rg];
    float* op = out_q + (rowbase + rg * 16 + lr) * DIM + g * 8;
#pragma unroll
    for (int c = 0; c < 4; c++) {
      int ps = (4 * c + g) ^ (code & 7);
      short8 e = *(const short8*)((char*)sm.emb + code * 256 + ps * 16);
      short8 xa = a[rg][c];
      float4 o0, o1;
#pragma unroll
      for (int j = 0; j < 4; j++) {
        float ef = bf2f((unsigned short)e[j]);
        float xf = bf2f((unsigned short)xa[j]);
        float d = ef - xf;
        lacc = fmaf(d, d, lacc);
        ((float*)&o0)[j] = ef;
      }
#pragma unroll
      for (int j = 0; j < 4; j++) {
        float ef = bf2f((unsigned short)e[4 + j]);
        float xf = bf2f((unsigned short)xa[4 + j]);
        float d = ef - xf;
        lacc = fmaf(d, d, lacc);
        ((float*)&o1)[j] = ef;
      }
      *(float4*)(op + c * 32) = o0;
      *(float4*)(op + c * 32 + 4) = o1;
    }
  }
#pragma unroll
  for (int m = 1; m < 64; m <<= 1) lacc += __shfl_xor(lacc, m);
  if (lane == 0) partials[blockIdx.x * NWAVES + wave] = lacc;
}

// ---------------- deterministic loss reduction ----------------
__global__ void vq_loss(const float* __restrict__ partials, float* __restrict__ out_loss) {
  __shared__ float red[16];
  const int t = threadIdx.x;
  float s = 0.f;
  for (int i = t; i < NBLOCKS * NWAVES; i += 1024) s += partials[i];
#pragma unroll
  for (int m = 1; m < 64; m <<= 1) s += __shfl_xor(s, m);
  if ((t & 63) == 0) red[t >> 6] = s;
  __syncthreads();
  if (t == 0) {
    float tot = 0.f;
    for (int i = 0; i < 16; i++) tot += red[i];
    // loss = q_latent + 0.6*e_latent = 1.6 * mean((q - x)^2)
    out_loss[0] = tot * (1.6f / (float)QN);
  }
}

extern "C" void kernel_launch(void* const* d_in, const int* in_sizes, int n_in,
                              void* d_out, int out_size, void* d_ws, size_t ws_size,
                              hipStream_t stream) {
  const float* x = (const float*)d_in[0];
  const float* emb = (const float*)d_in[1];
  const float* scaling = (const float*)d_in[2];

  float* out_q = (float*)d_out;
  float* out_loss = out_q + QN;
  float* out_idx = out_q + QN + 1;

  unsigned short* emb_bf = (unsigned short*)d_ws;
  float* wv = (float*)((char*)d_ws + NCODES * DIM * 2);
  float* wse = wv + NCODES;
  float* partials = wse + NCODES;

  vq_prep<<<NCODES, 64, 0, stream>>>(emb, scaling, emb_bf, wv, wse);
  vq_main<<<NBLOCKS, 1024, 0, stream>>>(x, emb_bf, wv, wse, out_q, out_idx, partials);
  vq_loss<<<1, 1024, 0, stream>>>(partials, out_loss);
}

// Round 2
// 65.240 us; speedup vs baseline: 1.1882x; 1.1882x over previous
//
#include <hip/hip_runtime.h>

#define NCODES 512
#define DIM 128
#define NROWS (64*2048)          // 131072
#define QN (NROWS*DIM)           // 16777216
#define BLK_ROWS 512
#define NBLOCKS (NROWS/BLK_ROWS) // 256
#define NWAVES 16

typedef __attribute__((ext_vector_type(8))) short short8;
typedef __attribute__((ext_vector_type(4))) float f32x4;

__device__ __forceinline__ unsigned short f2bf(float f) {
  unsigned u = __builtin_bit_cast(unsigned, f);
  u += 0x7FFFu + ((u >> 16) & 1u);   // RNE
  return (unsigned short)(u >> 16);
}
__device__ __forceinline__ float bf2f(unsigned short h) {
  unsigned u = ((unsigned)h) << 16;
  return __builtin_bit_cast(float, u);
}

// ---------------- prep: bf16 codebook + per-code weights ----------------
__global__ void vq_prep(const float* __restrict__ emb, const float* __restrict__ scaling,
                        unsigned short* __restrict__ emb_bf,
                        float* __restrict__ wv, float* __restrict__ wse) {
  int k = blockIdx.x;
  int l = threadIdx.x; // 64 lanes
  float2 v = ((const float2*)(emb + k * DIM))[l];
  float ss = v.x * v.x + v.y * v.y;
#pragma unroll
  for (int m = 1; m < 64; m <<= 1) ss += __shfl_xor(ss, m);
  unsigned pack = (unsigned)f2bf(v.x) | ((unsigned)f2bf(v.y) << 16);
  ((unsigned*)emb_bf)[k * 64 + l] = pack;
  if (l == 0) {
    float hr = 40.0f + (float)k * (140.0f / 511.0f);
    float wt = 1.0f + scaling[k] * ((hr - 100.0f) * (1.0f / 70.0f));
    wv[k] = wt;
    wse[k] = wt * ss;  // w_k * ||e_k||^2
  }
}

// ---------------- main ----------------
// LDS codebook is FRAGMENT-ORDERED: slice (t,c) = 1024B contiguous, lane l's
// 16B at offset l*16. l=(g,lr): holds code t*16+lr, k-chunk c*32+g*8.
// Main-loop ds_read_b128 is then a contiguous wave read -> conflict-free.
struct SmemT {
  unsigned short frag[NCODES * DIM]; // 131072 B
  float w[NCODES];
  float wse[NCODES];
};

__global__ __launch_bounds__(1024, 4) void vq_main(
    const float* __restrict__ x,
    const unsigned short* __restrict__ emb_bf,
    const float* __restrict__ wv,
    const float* __restrict__ wse,
    float* __restrict__ out_q,
    float* __restrict__ out_idx,
    float* __restrict__ partials) {
  __shared__ SmemT sm;
  const int tid = threadIdx.x;
  const int wave = tid >> 6, lane = tid & 63;
  const int g = lane >> 4, lr = lane & 15;
  const long rowbase = (long)blockIdx.x * BLK_ROWS + wave * 32;

  // --- Issue x loads FIRST (T14 issue-early): HBM latency hides under staging.
  float4 xv[2][4][2];
#pragma unroll
  for (int rg = 0; rg < 2; rg++) {
    const float* xr = x + (rowbase + rg * 16 + lr) * DIM + g * 8;
#pragma unroll
    for (int c = 0; c < 4; c++) {
      xv[rg][c][0] = *(const float4*)(xr + c * 32);
      xv[rg][c][1] = *(const float4*)(xr + c * 32 + 4);
    }
  }

  // --- Stage codebook into LDS, fragment-ordered, dest-contiguous writes.
  {
    const uint4* src = (const uint4*)emb_bf;
    uint4* dst = (uint4*)sm.frag;
#pragma unroll
    for (int i = 0; i < 8; i++) {
      int d = tid + i * 1024;            // dest 16B-slot, 0..8191
      int t = d >> 8;
      int c = (d >> 6) & 3;
      int gg = (d >> 4) & 3;
      int rr = d & 15;
      int s = (t * 16 + rr) * 16 + c * 4 + gg;  // source 16B-slot (row-major)
      dst[d] = src[s];
    }
    if (tid < NCODES) { sm.w[tid] = wv[tid]; sm.wse[tid] = wse[tid]; }
  }
  __syncthreads();

  // --- Convert x to A fragments + row sumsq.
  short8 a[2][4];
  float sr[2][4];
  {
    float srow[2];
#pragma unroll
    for (int rg = 0; rg < 2; rg++) {
      float ss = 0.f;
#pragma unroll
      for (int c = 0; c < 4; c++) {
        float4 v0 = xv[rg][c][0];
        float4 v1 = xv[rg][c][1];
        ss += v0.x * v0.x + v0.y * v0.y + v0.z * v0.z + v0.w * v0.w;
        ss += v1.x * v1.x + v1.y * v1.y + v1.z * v1.z + v1.w * v1.w;
        short8 av;
        av[0] = (short)f2bf(v0.x); av[1] = (short)f2bf(v0.y);
        av[2] = (short)f2bf(v0.z); av[3] = (short)f2bf(v0.w);
        av[4] = (short)f2bf(v1.x); av[5] = (short)f2bf(v1.y);
        av[6] = (short)f2bf(v1.z); av[7] = (short)f2bf(v1.w);
        a[rg][c] = av;
      }
      ss += __shfl_xor(ss, 16);
      ss += __shfl_xor(ss, 32);
      srow[rg] = ss;
    }
#pragma unroll
    for (int rg = 0; rg < 2; rg++)
#pragma unroll
      for (int r = 0; r < 4; r++)
        sr[rg][r] = __shfl(srow[rg], g * 4 + r);  // s of C-row 4g+r
  }

  // --- Sweep 32 column tiles of 16 codes; running weighted-argmin per lane.
  float vmin[2][4];
  int imin[2][4];
#pragma unroll
  for (int rg = 0; rg < 2; rg++)
#pragma unroll
    for (int r = 0; r < 4; r++) { vmin[rg][r] = 3.0e38f; imin[rg][r] = 0; }

  const short8* __restrict__ bbase = (const short8*)sm.frag + lane;
  for (int t = 0; t < 32; t++) {
    const int code = t * 16 + lr;         // B col = lane&15
    const float wt = sm.w[code];
    const float bb = sm.wse[code];
    const float m2w = -2.0f * wt;
    f32x4 acc0 = {0.f, 0.f, 0.f, 0.f};
    f32x4 acc1 = {0.f, 0.f, 0.f, 0.f};
#pragma unroll
    for (int c = 0; c < 4; c++) {
      short8 bf = bbase[(t * 4 + c) * 64];
      acc0 = __builtin_amdgcn_mfma_f32_16x16x32_bf16(a[0][c], bf, acc0, 0, 0, 0);
      acc1 = __builtin_amdgcn_mfma_f32_16x16x32_bf16(a[1][c], bf, acc1, 0, 0, 0);
    }
#pragma unroll
    for (int r = 0; r < 4; r++) {
      float v0 = fmaf(m2w, acc0[r], fmaf(wt, sr[0][r], bb));
      float v1 = fmaf(m2w, acc1[r], fmaf(wt, sr[1][r], bb));
      if (v0 < vmin[0][r]) { vmin[0][r] = v0; imin[0][r] = code; }
      if (v1 < vmin[1][r]) { vmin[1][r] = v1; imin[1][r] = code; }
    }
  }

  // --- Butterfly min-reduce across 16 lanes (tie -> smaller index).
#pragma unroll
  for (int m = 1; m <= 8; m <<= 1) {
#pragma unroll
    for (int rg = 0; rg < 2; rg++)
#pragma unroll
      for (int r = 0; r < 4; r++) {
        float ov = __shfl_xor(vmin[rg][r], m);
        int oi = __shfl_xor(imin[rg][r], m);
        if (ov < vmin[rg][r] || (ov == vmin[rg][r] && oi < imin[rg][r])) {
          vmin[rg][r] = ov; imin[rg][r] = oi;
        }
      }
  }

  // --- Write indices (as float).
  if (lr == 0) {
#pragma unroll
    for (int rg = 0; rg < 2; rg++)
#pragma unroll
      for (int r = 0; r < 4; r++)
        out_idx[rowbase + rg * 16 + g * 4 + r] = (float)imin[rg][r];
  }

  // --- Winning index for THIS lane's A-rows (row = lane&15).
  int myidx[2];
  {
    const int srcl = (lr >> 2) << 4;
    const int sel = lr & 3;
#pragma unroll
    for (int rg = 0; rg < 2; rg++) {
      int c0 = __shfl(imin[rg][0], srcl);
      int c1 = __shfl(imin[rg][1], srcl);
      int c2 = __shfl(imin[rg][2], srcl);
      int c3 = __shfl(imin[rg][3], srcl);
      int lo = (sel & 1) ? c1 : c0;
      int hi = (sel & 1) ? c3 : c2;
      myidx[rg] = (sel & 2) ? hi : lo;
    }
  }

  // --- Quantized output (gather from fragment-ordered LDS) + loss.
  float lacc = 0.f;
#pragma unroll
  for (int rg = 0; rg < 2; rg++) {
    const int code = myidx[rg];
    const int tt = code >> 4, rr = code & 15;
    float* op = out_q + (rowbase + rg * 16 + lr) * DIM + g * 8;
#pragma unroll
    for (int c = 0; c < 4; c++) {
      short8 e = ((const short8*)sm.frag)[(tt * 4 + c) * 64 + g * 16 + rr];
      short8 xa = a[rg][c];
      float4 o0, o1;
#pragma unroll
      for (int j = 0; j < 4; j++) {
        float ef = bf2f((unsigned short)e[j]);
        float xf = bf2f((unsigned short)xa[j]);
        float d = ef - xf;
        lacc = fmaf(d, d, lacc);
        ((float*)&o0)[j] = ef;
      }
#pragma unroll
      for (int j = 0; j < 4; j++) {
        float ef = bf2f((unsigned short)e[4 + j]);
        float xf = bf2f((unsigned short)xa[4 + j]);
        float d = ef - xf;
        lacc = fmaf(d, d, lacc);
        ((float*)&o1)[j] = ef;
      }
      *(float4*)(op + c * 32) = o0;
      *(float4*)(op + c * 32 + 4) = o1;
    }
  }
#pragma unroll
  for (int m = 1; m < 64; m <<= 1) lacc += __shfl_xor(lacc, m);
  if (lane == 0) partials[blockIdx.x * NWAVES + wave] = lacc;
}

// ---------------- deterministic loss reduction ----------------
__global__ void vq_loss(const float* __restrict__ partials, float* __restrict__ out_loss) {
  __shared__ float red[16];
  const int t = threadIdx.x;
  float s = 0.f;
  for (int i = t; i < NBLOCKS * NWAVES; i += 1024) s += partials[i];
#pragma unroll
  for (int m = 1; m < 64; m <<= 1) s += __shfl_xor(s, m);
  if ((t & 63) == 0) red[t >> 6] = s;
  __syncthreads();
  if (t == 0) {
    float tot = 0.f;
    for (int i = 0; i < 16; i++) tot += red[i];
    out_loss[0] = tot * (1.6f / (float)QN);
  }
}

extern "C" void kernel_launch(void* const* d_in, const int* in_sizes, int n_in,
                              void* d_out, int out_size, void* d_ws, size_t ws_size,
                              hipStream_t stream) {
  const float* x = (const float*)d_in[0];
  const float* emb = (const float*)d_in[1];
  const float* scaling = (const float*)d_in[2];

  float* out_q = (float*)d_out;
  float* out_loss = out_q + QN;
  float* out_idx = out_q + QN + 1;

  unsigned short* emb_bf = (unsigned short*)d_ws;
  float* wv = (float*)((char*)d_ws + NCODES * DIM * 2);
  float* wse = wv + NCODES;
  float* partials = wse + NCODES;

  vq_prep<<<NCODES, 64, 0, stream>>>(emb, scaling, emb_bf, wv, wse);
  vq_main<<<NBLOCKS, 1024, 0, stream>>>(x, emb_bf, wv, wse, out_q, out_idx, partials);
  vq_loss<<<1, 1024, 0, stream>>>(partials, out_loss);
}

// Round 4
// 55.307 us; speedup vs baseline: 1.4016x; 1.1796x over previous
//
#include <hip/hip_runtime.h>

#define NCODES 512
#define DIM 128
#define NROWS (64*2048)          // 131072
#define QN (NROWS*DIM)           // 16777216
#define BLK_ROWS 512
#define NBLOCKS (NROWS/BLK_ROWS) // 256
#define NWAVES 16

typedef __attribute__((ext_vector_type(8))) short short8;
typedef __attribute__((ext_vector_type(4))) float f32x4;

__device__ __forceinline__ unsigned short f2bf(float f) {
  unsigned u = __builtin_bit_cast(unsigned, f);
  u += 0x7FFFu + ((u >> 16) & 1u);   // RNE
  return (unsigned short)(u >> 16);
}

#define GLOAD_LDS16(gp, lp) __builtin_amdgcn_global_load_lds( \
    (__attribute__((address_space(1))) void*)(gp), \
    (__attribute__((address_space(3))) void*)(lp), 16, 0, 0)

// ---------------- prep: bf16 codebook + per-code weights ----------------
__global__ void vq_prep(const float* __restrict__ emb, const float* __restrict__ scaling,
                        unsigned short* __restrict__ emb_bf,
                        float* __restrict__ wv, float* __restrict__ wse,
                        float* __restrict__ wrcp) {
  int k = blockIdx.x;
  int l = threadIdx.x; // 64 lanes
  float2 v = ((const float2*)(emb + k * DIM))[l];
  float ss = v.x * v.x + v.y * v.y;
#pragma unroll
  for (int m = 1; m < 64; m <<= 1) ss += __shfl_xor(ss, m);
  unsigned pack = (unsigned)f2bf(v.x) | ((unsigned)f2bf(v.y) << 16);
  ((unsigned*)emb_bf)[k * 64 + l] = pack;
  if (l == 0) {
    float hr = 40.0f + (float)k * (140.0f / 511.0f);
    float wt = 1.0f + scaling[k] * ((hr - 100.0f) * (1.0f / 70.0f));
    wv[k] = wt;
    wse[k] = wt * ss;        // w_k * ||e_k||^2
    wrcp[k] = 1.0f / wt;     // exact IEEE divide, once per code
  }
}

// ---------------- main ----------------
// LDS codebook FRAGMENT-ORDERED: slice (t,c) = 1024B contiguous; lane l holds
// code t*16+(l&15), k-chunk c*32+(l>>4)*8. Sweep ds_read_b128 is contiguous
// per wave -> conflict-free. Staged via global_load_lds (pre-swizzled source).
struct SmemT {
  unsigned short frag[NCODES * DIM]; // 131072 B
  float w[NCODES];
  float wse[NCODES];
  float wrcp[NCODES];
  int idx[BLK_ROWS];
};

__global__ __launch_bounds__(1024, 4) void vq_main(
    const float* __restrict__ x,
    const float* __restrict__ emb32,
    const unsigned short* __restrict__ emb_bf,
    const float* __restrict__ wv,
    const float* __restrict__ wse,
    const float* __restrict__ wrcp,
    float* __restrict__ out_q,
    float* __restrict__ out_idx,
    float* __restrict__ partials) {
  __shared__ SmemT sm;
  const int tid = threadIdx.x;
  const int wave = tid >> 6, lane = tid & 63;
  const int g = lane >> 4, lr = lane & 15;
  const long rowbase = (long)blockIdx.x * BLK_ROWS + wave * 32;

  // --- Issue x loads (registers) ---
  float4 xv[2][4][2];
#pragma unroll
  for (int rg = 0; rg < 2; rg++) {
    const float* xr = x + (rowbase + rg * 16 + lr) * DIM + g * 8;
#pragma unroll
    for (int c = 0; c < 4; c++) {
      xv[rg][c][0] = *(const float4*)(xr + c * 32);
      xv[rg][c][1] = *(const float4*)(xr + c * 32 + 4);
    }
  }

  // --- Issue codebook staging: global_load_lds, frag-order via source swizzle.
  {
    const uint4* src = (const uint4*)emb_bf;
#pragma unroll
    for (int i = 0; i < 8; i++) {
      int winst = wave * 8 + i;
      int d = winst * 64 + lane;                 // dest 16B slot
      int t = d >> 8, c = (d >> 6) & 3, gg = (d >> 4) & 3, rr = d & 15;
      int s = (t * 16 + rr) * 16 + c * 4 + gg;   // source slot (row-major)
      GLOAD_LDS16(src + s, (char*)sm.frag + winst * 1024);
    }
    if (tid < NCODES) {
      sm.w[tid] = wv[tid];
      sm.wse[tid] = wse[tid];
      sm.wrcp[tid] = wrcp[tid];
    }
  }

  // --- Convert x to A fragments + row sumsq (overlaps staging latency).
  short8 a[2][4];
  float sr[2][4];
  {
    float srow[2];
#pragma unroll
    for (int rg = 0; rg < 2; rg++) {
      float ss = 0.f;
#pragma unroll
      for (int c = 0; c < 4; c++) {
        float4 v0 = xv[rg][c][0];
        float4 v1 = xv[rg][c][1];
        ss += v0.x * v0.x + v0.y * v0.y + v0.z * v0.z + v0.w * v0.w;
        ss += v1.x * v1.x + v1.y * v1.y + v1.z * v1.z + v1.w * v1.w;
        short8 av;
        av[0] = (short)f2bf(v0.x); av[1] = (short)f2bf(v0.y);
        av[2] = (short)f2bf(v0.z); av[3] = (short)f2bf(v0.w);
        av[4] = (short)f2bf(v1.x); av[5] = (short)f2bf(v1.y);
        av[6] = (short)f2bf(v1.z); av[7] = (short)f2bf(v1.w);
        a[rg][c] = av;
      }
      ss += __shfl_xor(ss, 16);
      ss += __shfl_xor(ss, 32);
      srow[rg] = ss;
    }
#pragma unroll
    for (int rg = 0; rg < 2; rg++)
#pragma unroll
      for (int r = 0; r < 4; r++)
        sr[rg][r] = __shfl(srow[rg], g * 4 + r);  // s of C-row 4g+r
  }
  __syncthreads();

  // --- Sweep 32 column tiles of 16 codes; running weighted-argmin per lane.
  float vmin[2][4];
  int imin[2][4];
#pragma unroll
  for (int rg = 0; rg < 2; rg++)
#pragma unroll
    for (int r = 0; r < 4; r++) { vmin[rg][r] = 3.0e38f; imin[rg][r] = 0; }

  const short8* __restrict__ bbase = (const short8*)sm.frag + lane;
  for (int t = 0; t < 32; t++) {
    const int code = t * 16 + lr;         // B col = lane&15
    const float wt = sm.w[code];
    const float bb = sm.wse[code];
    const float m2w = -2.0f * wt;
    f32x4 acc0 = {0.f, 0.f, 0.f, 0.f};
    f32x4 acc1 = {0.f, 0.f, 0.f, 0.f};
#pragma unroll
    for (int c = 0; c < 4; c++) {
      short8 bf = bbase[(t * 4 + c) * 64];
      acc0 = __builtin_amdgcn_mfma_f32_16x16x32_bf16(a[0][c], bf, acc0, 0, 0, 0);
      acc1 = __builtin_amdgcn_mfma_f32_16x16x32_bf16(a[1][c], bf, acc1, 0, 0, 0);
    }
#pragma unroll
    for (int r = 0; r < 4; r++) {
      float v0 = fmaf(m2w, acc0[r], fmaf(wt, sr[0][r], bb));
      float v1 = fmaf(m2w, acc1[r], fmaf(wt, sr[1][r], bb));
      if (v0 < vmin[0][r]) { vmin[0][r] = v0; imin[0][r] = code; }
      if (v1 < vmin[1][r]) { vmin[1][r] = v1; imin[1][r] = code; }
    }
  }

  // --- Butterfly min-reduce across 16 lanes (tie -> smaller index).
#pragma unroll
  for (int m = 1; m <= 8; m <<= 1) {
#pragma unroll
    for (int rg = 0; rg < 2; rg++)
#pragma unroll
      for (int r = 0; r < 4; r++) {
        float ov = __shfl_xor(vmin[rg][r], m);
        int oi = __shfl_xor(imin[rg][r], m);
        if (ov < vmin[rg][r] || (ov == vmin[rg][r] && oi < imin[rg][r])) {
          vmin[rg][r] = ov; imin[rg][r] = oi;
        }
      }
  }

  // --- Winner processing: loss via dist = vmin * (1/w[imin]); idx -> LDS.
  {
    float l0 = 0.f;
#pragma unroll
    for (int rg = 0; rg < 2; rg++)
#pragma unroll
      for (int r = 0; r < 4; r++) {
        int ci = imin[rg][r];
        l0 = fmaf(vmin[rg][r], sm.wrcp[ci], l0);
        if (lr == 0) sm.idx[wave * 32 + rg * 16 + g * 4 + r] = ci;
      }
    // All 16 lanes of a group hold the same l0 (8 rows); the two xors add
    // exactly one lane from each OTHER group -> sum over all 32 rows. No
    // replication factor (R3 bug was an erroneous /16 here).
    l0 += __shfl_xor(l0, 16);
    l0 += __shfl_xor(l0, 32);
    if (lane == 0) partials[blockIdx.x * NWAVES + wave] = l0;
  }
  __syncthreads();

  // --- Coalesced output: gather f32 codebook rows, contiguous uint4 stores.
  {
    const uint4* __restrict__ esrc = (const uint4*)emb32;   // 32 uint4 per row
    uint4* __restrict__ outu = (uint4*)(out_q + (long)blockIdx.x * BLK_ROWS * DIM);
#pragma unroll
    for (int i = 0; i < 16; i++) {
      int pos = i * 1024 + tid;       // uint4 index within block tile
      int row = pos >> 5, k = pos & 31;
      int code = sm.idx[row];
      outu[pos] = esrc[code * 32 + k];
    }
    if (tid < BLK_ROWS)
      out_idx[(long)blockIdx.x * BLK_ROWS + tid] = (float)sm.idx[tid];
  }
}

// ---------------- deterministic loss reduction ----------------
__global__ void vq_loss(const float* __restrict__ partials, float* __restrict__ out_loss) {
  __shared__ float red[16];
  const int t = threadIdx.x;
  float s = 0.f;
  for (int i = t; i < NBLOCKS * NWAVES; i += 1024) s += partials[i];
#pragma unroll
  for (int m = 1; m < 64; m <<= 1) s += __shfl_xor(s, m);
  if ((t & 63) == 0) red[t >> 6] = s;
  __syncthreads();
  if (t == 0) {
    float tot = 0.f;
    for (int i = 0; i < 16; i++) tot += red[i];
    // loss = (1 + 0.6) * mean((q - x)^2) over all QN elements
    out_loss[0] = tot * (1.6f / (float)QN);
  }
}

extern "C" void kernel_launch(void* const* d_in, const int* in_sizes, int n_in,
                              void* d_out, int out_size, void* d_ws, size_t ws_size,
                              hipStream_t stream) {
  const float* x = (const float*)d_in[0];
  const float* emb = (const float*)d_in[1];
  const float* scaling = (const float*)d_in[2];

  float* out_q = (float*)d_out;
  float* out_loss = out_q + QN;
  float* out_idx = out_q + QN + 1;

  unsigned short* emb_bf = (unsigned short*)d_ws;
  float* wv = (float*)((char*)d_ws + NCODES * DIM * 2);
  float* wse = wv + NCODES;
  float* wrcp = wse + NCODES;
  float* partials = wrcp + NCODES;

  vq_prep<<<NCODES, 64, 0, stream>>>(emb, scaling, emb_bf, wv, wse, wrcp);
  vq_main<<<NBLOCKS, 1024, 0, stream>>>(x, emb, emb_bf, wv, wse, wrcp,
                                        out_q, out_idx, partials);
  vq_loss<<<1, 1024, 0, stream>>>(partials, out_loss);
}